// Round 4
// baseline (349.833 us; speedup 1.0000x reference)
//
#include <hip/hip_runtime.h>

// N=64 nodes, H=64, M=32, B=16384.
// Grid: 1024 blocks = 64 i-values x 16 batch-groups -> exactly 4 blocks/CU,
// 4 waves/SIMD (VGPR<=128 via __launch_bounds__(256,4)). 4 waves/block; NO __shared__.
// All weights for node i live in registers as bf16 MFMA A-fragments, with the
// K-columns of W1b/W2b/W3a permuted (sigma) so each phase's MFMA D registers,
// after relu+bf16 pack, ARE the next phase's B-operand fragments in-register.
// Batch stays in lane&15 through the whole chain; no LDS round-trips at all.

typedef short bf16x8 __attribute__((ext_vector_type(8)));
typedef float f32x4  __attribute__((ext_vector_type(4)));
typedef unsigned int u32x4 __attribute__((ext_vector_type(4)));

__device__ __forceinline__ unsigned int pack2(float a, float b) {
    // f32->bf16 pair pack, round-to-nearest-ties-away: 2 adds + 1 v_perm (a -> low16)
    union { float f; unsigned int u; } ua, ub; ua.f = a; ub.f = b;
    return __builtin_amdgcn_perm(ub.u + 0x8000u, ua.u + 0x8000u, 0x07060302u);
}

__device__ __forceinline__ f32x4 mfma16(bf16x8 a, bf16x8 b, f32x4 c) {
    return __builtin_amdgcn_mfma_f32_16x16x32_bf16(a, b, c, 0, 0, 0);
}

// pack two relu'd f32x4 D-blocks into one bf16x8 B-operand fragment
__device__ __forceinline__ bf16x8 pack_frag(f32x4 lo, f32x4 hi) {
    union { u32x4 u; bf16x8 v; } r;
    r.u[0] = pack2(fmaxf(lo[0], 0.f), fmaxf(lo[1], 0.f));
    r.u[1] = pack2(fmaxf(lo[2], 0.f), fmaxf(lo[3], 0.f));
    r.u[2] = pack2(fmaxf(hi[0], 0.f), fmaxf(hi[1], 0.f));
    r.u[3] = pack2(fmaxf(hi[2], 0.f), fmaxf(hi[3], 0.f));
    return r.v;
}

// convert 2x f32x4 (possibly non-adjacent) into a bf16x8 A-fragment
__device__ __forceinline__ bf16x8 cvt_frag2(const float* __restrict__ plo,
                                            const float* __restrict__ phi) {
    f32x4 f0 = *(const f32x4*)plo;
    f32x4 f1 = *(const f32x4*)phi;
    union { u32x4 u; bf16x8 v; } r;
    r.u[0] = pack2(f0[0], f0[1]);
    r.u[1] = pack2(f0[2], f0[3]);
    r.u[2] = pack2(f1[0], f1[1]);
    r.u[3] = pack2(f1[2], f1[3]);
    return r.v;
}

__device__ __forceinline__ bf16x8 cvt_frag2_m(const float* __restrict__ plo,
                                              const float* __restrict__ phi,
                                              const unsigned int* M) {
    f32x4 f0 = *(const f32x4*)plo;
    f32x4 f1 = *(const f32x4*)phi;
    union { u32x4 u; bf16x8 v; } r;
    r.u[0] = pack2(f0[0], f0[1]) & M[0];
    r.u[1] = pack2(f0[2], f0[3]) & M[1];
    r.u[2] = pack2(f1[0], f1[1]) & M[2];
    r.u[3] = pack2(f1[2], f1[3]) & M[3];
    return r.v;
}

__global__ __launch_bounds__(256) void prep_x(const float* __restrict__ x,
                                              unsigned short* __restrict__ xb) {
    int j = (blockIdx.x * 256 + threadIdx.x) * 8;
    f32x4 a = *(const f32x4*)&x[j];
    f32x4 b = *(const f32x4*)&x[j + 4];
    u32x4 r = { pack2(a[0], a[1]), pack2(a[2], a[3]), pack2(b[0], b[1]), pack2(b[2], b[3]) };
    *(u32x4*)&xb[j] = r;
}

__global__ __launch_bounds__(256, 4) void main_kernel(
    const float* __restrict__ x,
    const float* __restrict__ W1a, const float* __restrict__ W1b,
    const float* __restrict__ W2a, const float* __restrict__ W2b,
    const float* __restrict__ W3a, const float* __restrict__ b3a,
    const float* __restrict__ W3b, const float* __restrict__ b3b,
    const unsigned short* __restrict__ xb,
    float* __restrict__ out)
{
    const int i    = blockIdx.x & 63;   // same-i blocks -> same XCD (stride 64 % 8 == 0)
    const int bg   = blockIdx.x >> 6;   // 0..15
    const int tid  = threadIdx.x;
    const int w    = tid >> 6;
    const int lane = tid & 63;
    const int q    = lane >> 4;
    const int c0   = lane & 15;

    // masks zeroing weight input-column i of W1a/W2a (== masking x column i)
    unsigned int M[2][4];
    {
        const unsigned int halfmask = (i & 1) ? 0x0000FFFFu : 0xFFFF0000u;
        const int dz = (i >> 1) & 3;
        #pragma unroll
        for (int s = 0; s < 2; ++s) {
            bool hit = ((i >> 3) == s * 4 + q);
            #pragma unroll
            for (int d = 0; d < 4; ++d)
                M[s][d] = (hit && d == dz) ? halfmask : 0xFFFFFFFFu;
        }
    }

    // ---- weights for node i -> registers (bf16 A-fragments), K-permuted where needed ----
    // Phase A (W1a/W2a): natural K order. frag elem j = W[i][t*16+c0][s*32+q*8+j]
    bf16x8 A1[4][2], A2[4][2];
    {
        const float* p1 = W1a + (i << 12);
        const float* p2 = W2a + (i << 12);
        #pragma unroll
        for (int t = 0; t < 4; ++t)
            #pragma unroll
            for (int s = 0; s < 2; ++s) {
                int off = (((t << 4) + c0) << 6) + (s << 5) + (q << 3);
                A1[t][s] = cvt_frag2_m(p1 + off, p1 + off + 4, M[s]);
                A2[t][s] = cvt_frag2_m(p2 + off, p2 + off + 4, M[s]);
            }
    }
    // Phase B (W1b/W2b): K permuted by sigma(s,q,j) = 32s + 16*(j>>2) + 4q + (j&3)
    bf16x8 F1[2][2], F2[2][2];
    {
        const float* p1 = W1b + (i << 11);
        const float* p2 = W2b + (i << 11);
        #pragma unroll
        for (int t = 0; t < 2; ++t)
            #pragma unroll
            for (int s = 0; s < 2; ++s) {
                int base = (((t << 4) + c0) << 6) + (s << 5) + (q << 2);
                F1[t][s] = cvt_frag2(p1 + base, p1 + base + 16);
                F2[t][s] = cvt_frag2(p2 + base, p2 + base + 16);
            }
    }
    // Phase C (W3a, first 64 concat cols): col = 32s + 16*(j>>2) + 4q + (j&3)
    bf16x8 A3[4][2];
    {
        const float* p3 = W3a + (i << 13);
        #pragma unroll
        for (int t = 0; t < 4; ++t)
            #pragma unroll
            for (int s = 0; s < 2; ++s) {
                int base = (((t << 4) + c0) << 7) + (s << 5) + (q << 2);
                A3[t][s] = cvt_frag2(p3 + base, p3 + base + 16);
            }
    }
    f32x4 b3av[4], w3xv[4], w3bv[4];
    #pragma unroll
    for (int t = 0; t < 4; ++t) {
        int h0 = (i << 6) + (t << 4) + (q << 2);
        b3av[t] = *(const f32x4*)&b3a[h0];
        w3bv[t] = *(const f32x4*)&W3b[h0];
        #pragma unroll
        for (int r = 0; r < 4; ++r)
            w3xv[t][r] = W3a[(i << 13) + (((t << 4) + (q << 2) + r) << 7) + 64 + i];
    }
    const float bb = b3b[i];

    // this wave's 256 batch rows (16 chunks of 16)
    const int r0 = (((bg << 2) + w) << 8) + c0;
    const unsigned short* xp = xb + (r0 << 6);
    const float*          dp = x  + (r0 << 6) + i;
    float*                op = out + (r0 << 6) + i;

    // prefetch chunk 0
    bf16x8 XB0 = *(const bf16x8*)&xp[(q << 3)];
    bf16x8 XB1 = *(const bf16x8*)&xp[32 + (q << 3)];
    float   xd = *dp;

    for (int k = 0; k < 16; ++k) {
        int adv = (k < 15) ? 1024 : 0;     // 16 rows * 64 cols
        const unsigned short* xpn = xp + adv;
        const float*          dpn = dp + adv;
        bf16x8 nXB0 = *(const bf16x8*)&xpn[(q << 3)];
        bf16x8 nXB1 = *(const bf16x8*)&xpn[32 + (q << 3)];
        float   nxd = *dpn;

        // ---- phase A: x -> Ha (W1a), x -> Hb (W2a); D regs -> B-frags in-register ----
        f32x4 a1[4], a2[4];
        #pragma unroll
        for (int t = 0; t < 4; ++t) {
            f32x4 z = {0.f, 0.f, 0.f, 0.f};
            f32x4 u = mfma16(A1[t][0], XB0, z);
            a1[t]   = mfma16(A1[t][1], XB1, u);
            f32x4 v = mfma16(A2[t][0], XB0, z);
            a2[t]   = mfma16(A2[t][1], XB1, v);
        }
        bf16x8 HB0 = pack_frag(a1[0], a1[1]);
        bf16x8 HB1 = pack_frag(a1[2], a1[3]);
        bf16x8 GB0 = pack_frag(a2[0], a2[1]);
        bf16x8 GB1 = pack_frag(a2[2], a2[3]);

        // ---- phase B: Ha -> r1 (W1b), Hb -> r2 (W2b) ----
        f32x4 b1[2], b2[2];
        #pragma unroll
        for (int t = 0; t < 2; ++t) {
            f32x4 z = {0.f, 0.f, 0.f, 0.f};
            f32x4 u = mfma16(F1[t][0], HB0, z);
            b1[t]   = mfma16(F1[t][1], HB1, u);
            f32x4 v = mfma16(F2[t][0], GB0, z);
            b2[t]   = mfma16(F2[t][1], GB1, v);
        }
        bf16x8 RB0 = pack_frag(b1[0], b1[1]);   // r1 -> A3 s=0 slots
        bf16x8 RB1 = pack_frag(b2[0], b2[1]);   // r2 -> A3 s=1 slots

        // ---- phase C: h = W3a'*[r1;r2] + xd*w3x + b3a; out = relu(dot(relu(h), w3b) + bb) ----
        float p = 0.f;
        #pragma unroll
        for (int t = 0; t < 4; ++t) {
            f32x4 acc;
            #pragma unroll
            for (int r = 0; r < 4; ++r) acc[r] = fmaf(xd, w3xv[t][r], b3av[t][r]);
            acc = mfma16(A3[t][0], RB0, acc);
            acc = mfma16(A3[t][1], RB1, acc);
            #pragma unroll
            for (int r = 0; r < 4; ++r) p = fmaf(fmaxf(acc[r], 0.f), w3bv[t][r], p);
        }
        p += __shfl_xor(p, 16);
        p += __shfl_xor(p, 32);
        if (lane < 16) *op = fmaxf(p + bb, 0.f);

        op += 1024;
        xp = xpn; dp = dpn; XB0 = nXB0; XB1 = nXB1; xd = nxd;
    }
}

extern "C" void kernel_launch(void* const* d_in, const int* in_sizes, int n_in,
                              void* d_out, int out_size, void* d_ws, size_t ws_size,
                              hipStream_t stream) {
    (void)in_sizes; (void)n_in; (void)out_size; (void)ws_size;
    const float* x   = (const float*)d_in[0];
    const float* W1a = (const float*)d_in[1];
    const float* W1b = (const float*)d_in[2];
    const float* W2a = (const float*)d_in[3];
    const float* W2b = (const float*)d_in[4];
    const float* W3a = (const float*)d_in[5];
    const float* b3a = (const float*)d_in[6];
    const float* W3b = (const float*)d_in[7];
    const float* b3b = (const float*)d_in[8];
    float* out = (float*)d_out;
    unsigned short* xb = (unsigned short*)d_ws;

    prep_x<<<512, 256, 0, stream>>>(x, xb);
    main_kernel<<<1024, 256, 0, stream>>>(x, W1a, W1b, W2a, W2b, W3a, b3a, W3b, b3b, xb, out);
}

// Round 5
// 144.047 us; speedup vs baseline: 2.4286x; 2.4286x over previous
//
#include <hip/hip_runtime.h>

// N=64 nodes, H=64, M=32, B=16384.
// Grid: 1024 blocks = 64 i-values x 16 batch-groups -> 4 blocks/CU. VGPR=112 fits
// 4 waves/SIMD naturally; launch_bounds kept at (256,2) so the allocator does NOT
// spill the register-resident weights (R4 lesson: (256,4) forced VGPR=64 -> 1 GB
// of scratch spill traffic, 4x regression).
// 4 waves/block; NO __shared__. All weights for node i live in registers as bf16
// MFMA A-fragments, with K-columns of W1b/W2b/W3a permuted (sigma) so each phase's
// MFMA D registers, after relu+bf16 pack, ARE the next phase's B-operand fragments.
// Batch stays in lane&15 through the whole chain; zero LDS traffic.

typedef short bf16x8 __attribute__((ext_vector_type(8)));
typedef float f32x4  __attribute__((ext_vector_type(4)));
typedef unsigned int u32x4 __attribute__((ext_vector_type(4)));

__device__ __forceinline__ unsigned int pack2(float a, float b) {
    // f32->bf16 pair pack, round-to-nearest-ties-away: 2 adds + 1 v_perm (a -> low16)
    union { float f; unsigned int u; } ua, ub; ua.f = a; ub.f = b;
    return __builtin_amdgcn_perm(ub.u + 0x8000u, ua.u + 0x8000u, 0x07060302u);
}

__device__ __forceinline__ f32x4 mfma16(bf16x8 a, bf16x8 b, f32x4 c) {
    return __builtin_amdgcn_mfma_f32_16x16x32_bf16(a, b, c, 0, 0, 0);
}

// pack two relu'd f32x4 D-blocks into one bf16x8 B-operand fragment
__device__ __forceinline__ bf16x8 pack_frag(f32x4 lo, f32x4 hi) {
    union { u32x4 u; bf16x8 v; } r;
    r.u[0] = pack2(fmaxf(lo[0], 0.f), fmaxf(lo[1], 0.f));
    r.u[1] = pack2(fmaxf(lo[2], 0.f), fmaxf(lo[3], 0.f));
    r.u[2] = pack2(fmaxf(hi[0], 0.f), fmaxf(hi[1], 0.f));
    r.u[3] = pack2(fmaxf(hi[2], 0.f), fmaxf(hi[3], 0.f));
    return r.v;
}

// convert 2x f32x4 (possibly non-adjacent) into a bf16x8 A-fragment
__device__ __forceinline__ bf16x8 cvt_frag2(const float* __restrict__ plo,
                                            const float* __restrict__ phi) {
    f32x4 f0 = *(const f32x4*)plo;
    f32x4 f1 = *(const f32x4*)phi;
    union { u32x4 u; bf16x8 v; } r;
    r.u[0] = pack2(f0[0], f0[1]);
    r.u[1] = pack2(f0[2], f0[3]);
    r.u[2] = pack2(f1[0], f1[1]);
    r.u[3] = pack2(f1[2], f1[3]);
    return r.v;
}

__device__ __forceinline__ bf16x8 cvt_frag2_m(const float* __restrict__ plo,
                                              const float* __restrict__ phi,
                                              const unsigned int* M) {
    f32x4 f0 = *(const f32x4*)plo;
    f32x4 f1 = *(const f32x4*)phi;
    union { u32x4 u; bf16x8 v; } r;
    r.u[0] = pack2(f0[0], f0[1]) & M[0];
    r.u[1] = pack2(f0[2], f0[3]) & M[1];
    r.u[2] = pack2(f1[0], f1[1]) & M[2];
    r.u[3] = pack2(f1[2], f1[3]) & M[3];
    return r.v;
}

__global__ __launch_bounds__(256) void prep_x(const float* __restrict__ x,
                                              unsigned short* __restrict__ xb) {
    int j = (blockIdx.x * 256 + threadIdx.x) * 8;
    f32x4 a = *(const f32x4*)&x[j];
    f32x4 b = *(const f32x4*)&x[j + 4];
    u32x4 r = { pack2(a[0], a[1]), pack2(a[2], a[3]), pack2(b[0], b[1]), pack2(b[2], b[3]) };
    *(u32x4*)&xb[j] = r;
}

__global__ __launch_bounds__(256, 2) void main_kernel(
    const float* __restrict__ x,
    const float* __restrict__ W1a, const float* __restrict__ W1b,
    const float* __restrict__ W2a, const float* __restrict__ W2b,
    const float* __restrict__ W3a, const float* __restrict__ b3a,
    const float* __restrict__ W3b, const float* __restrict__ b3b,
    const unsigned short* __restrict__ xb,
    float* __restrict__ out)
{
    const int i    = blockIdx.x & 63;   // same-i blocks -> same XCD (stride 64 % 8 == 0)
    const int bg   = blockIdx.x >> 6;   // 0..15
    const int tid  = threadIdx.x;
    const int w    = tid >> 6;
    const int lane = tid & 63;
    const int q    = lane >> 4;
    const int c0   = lane & 15;

    // masks zeroing weight input-column i of W1a/W2a (== masking x column i)
    unsigned int M[2][4];
    {
        const unsigned int halfmask = (i & 1) ? 0x0000FFFFu : 0xFFFF0000u;
        const int dz = (i >> 1) & 3;
        #pragma unroll
        for (int s = 0; s < 2; ++s) {
            bool hit = ((i >> 3) == s * 4 + q);
            #pragma unroll
            for (int d = 0; d < 4; ++d)
                M[s][d] = (hit && d == dz) ? halfmask : 0xFFFFFFFFu;
        }
    }

    // ---- weights for node i -> registers (bf16 A-fragments), K-permuted where needed ----
    // Phase A (W1a/W2a): natural K order. frag elem j = W[i][t*16+c0][s*32+q*8+j]
    bf16x8 A1[4][2], A2[4][2];
    {
        const float* p1 = W1a + (i << 12);
        const float* p2 = W2a + (i << 12);
        #pragma unroll
        for (int t = 0; t < 4; ++t)
            #pragma unroll
            for (int s = 0; s < 2; ++s) {
                int off = (((t << 4) + c0) << 6) + (s << 5) + (q << 3);
                A1[t][s] = cvt_frag2_m(p1 + off, p1 + off + 4, M[s]);
                A2[t][s] = cvt_frag2_m(p2 + off, p2 + off + 4, M[s]);
            }
    }
    // Phase B (W1b/W2b): K permuted by sigma(s,q,j) = 32s + 16*(j>>2) + 4q + (j&3)
    bf16x8 F1[2][2], F2[2][2];
    {
        const float* p1 = W1b + (i << 11);
        const float* p2 = W2b + (i << 11);
        #pragma unroll
        for (int t = 0; t < 2; ++t)
            #pragma unroll
            for (int s = 0; s < 2; ++s) {
                int base = (((t << 4) + c0) << 6) + (s << 5) + (q << 2);
                F1[t][s] = cvt_frag2(p1 + base, p1 + base + 16);
                F2[t][s] = cvt_frag2(p2 + base, p2 + base + 16);
            }
    }
    // Phase C (W3a, first 64 concat cols): col = 32s + 16*(j>>2) + 4q + (j&3)
    bf16x8 A3[4][2];
    {
        const float* p3 = W3a + (i << 13);
        #pragma unroll
        for (int t = 0; t < 4; ++t)
            #pragma unroll
            for (int s = 0; s < 2; ++s) {
                int base = (((t << 4) + c0) << 7) + (s << 5) + (q << 2);
                A3[t][s] = cvt_frag2(p3 + base, p3 + base + 16);
            }
    }
    f32x4 b3av[4], w3xv[4], w3bv[4];
    #pragma unroll
    for (int t = 0; t < 4; ++t) {
        int h0 = (i << 6) + (t << 4) + (q << 2);
        b3av[t] = *(const f32x4*)&b3a[h0];
        w3bv[t] = *(const f32x4*)&W3b[h0];
        #pragma unroll
        for (int r = 0; r < 4; ++r)
            w3xv[t][r] = W3a[(i << 13) + (((t << 4) + (q << 2) + r) << 7) + 64 + i];
    }
    const float bb = b3b[i];

    // this wave's 256 batch rows (16 chunks of 16)
    const int r0 = (((bg << 2) + w) << 8) + c0;
    const unsigned short* xp = xb + (r0 << 6);
    const float*          dp = x  + (r0 << 6) + i;
    float*                op = out + (r0 << 6) + i;

    // prefetch chunk 0
    bf16x8 XB0 = *(const bf16x8*)&xp[(q << 3)];
    bf16x8 XB1 = *(const bf16x8*)&xp[32 + (q << 3)];
    float   xd = *dp;

    for (int k = 0; k < 16; ++k) {
        int adv = (k < 15) ? 1024 : 0;     // 16 rows * 64 cols
        const unsigned short* xpn = xp + adv;
        const float*          dpn = dp + adv;
        bf16x8 nXB0 = *(const bf16x8*)&xpn[(q << 3)];
        bf16x8 nXB1 = *(const bf16x8*)&xpn[32 + (q << 3)];
        float   nxd = *dpn;

        // ---- phase A: x -> Ha (W1a), x -> Hb (W2a); D regs -> B-frags in-register ----
        f32x4 a1[4], a2[4];
        #pragma unroll
        for (int t = 0; t < 4; ++t) {
            f32x4 z = {0.f, 0.f, 0.f, 0.f};
            f32x4 u = mfma16(A1[t][0], XB0, z);
            a1[t]   = mfma16(A1[t][1], XB1, u);
            f32x4 v = mfma16(A2[t][0], XB0, z);
            a2[t]   = mfma16(A2[t][1], XB1, v);
        }
        bf16x8 HB0 = pack_frag(a1[0], a1[1]);
        bf16x8 HB1 = pack_frag(a1[2], a1[3]);
        bf16x8 GB0 = pack_frag(a2[0], a2[1]);
        bf16x8 GB1 = pack_frag(a2[2], a2[3]);

        // ---- phase B: Ha -> r1 (W1b), Hb -> r2 (W2b) ----
        f32x4 b1[2], b2[2];
        #pragma unroll
        for (int t = 0; t < 2; ++t) {
            f32x4 z = {0.f, 0.f, 0.f, 0.f};
            f32x4 u = mfma16(F1[t][0], HB0, z);
            b1[t]   = mfma16(F1[t][1], HB1, u);
            f32x4 v = mfma16(F2[t][0], GB0, z);
            b2[t]   = mfma16(F2[t][1], GB1, v);
        }
        bf16x8 RB0 = pack_frag(b1[0], b1[1]);   // r1 -> A3 s=0 slots
        bf16x8 RB1 = pack_frag(b2[0], b2[1]);   // r2 -> A3 s=1 slots

        // ---- phase C: h = W3a'*[r1;r2] + xd*w3x + b3a; out = relu(dot(relu(h), w3b) + bb) ----
        float p = 0.f;
        #pragma unroll
        for (int t = 0; t < 4; ++t) {
            f32x4 acc;
            #pragma unroll
            for (int r = 0; r < 4; ++r) acc[r] = fmaf(xd, w3xv[t][r], b3av[t][r]);
            acc = mfma16(A3[t][0], RB0, acc);
            acc = mfma16(A3[t][1], RB1, acc);
            #pragma unroll
            for (int r = 0; r < 4; ++r) p = fmaf(fmaxf(acc[r], 0.f), w3bv[t][r], p);
        }
        p += __shfl_xor(p, 16);
        p += __shfl_xor(p, 32);
        if (lane < 16) *op = fmaxf(p + bb, 0.f);

        op += 1024;
        xp = xpn; dp = dpn; XB0 = nXB0; XB1 = nXB1; xd = nxd;
    }
}

extern "C" void kernel_launch(void* const* d_in, const int* in_sizes, int n_in,
                              void* d_out, int out_size, void* d_ws, size_t ws_size,
                              hipStream_t stream) {
    (void)in_sizes; (void)n_in; (void)out_size; (void)ws_size;
    const float* x   = (const float*)d_in[0];
    const float* W1a = (const float*)d_in[1];
    const float* W1b = (const float*)d_in[2];
    const float* W2a = (const float*)d_in[3];
    const float* W2b = (const float*)d_in[4];
    const float* W3a = (const float*)d_in[5];
    const float* b3a = (const float*)d_in[6];
    const float* W3b = (const float*)d_in[7];
    const float* b3b = (const float*)d_in[8];
    float* out = (float*)d_out;
    unsigned short* xb = (unsigned short*)d_ws;

    prep_x<<<512, 256, 0, stream>>>(x, xb);
    main_kernel<<<1024, 256, 0, stream>>>(x, W1a, W1b, W2a, W2b, W3a, b3a, W3b, b3b, xb, out);
}